// Round 3
// baseline (10759.061 us; speedup 1.0000x reference)
//
#include <hip/hip_runtime.h>
#include <hip/hip_bf16.h>

// Inputs/outputs are FLOAT32 (per reference). Compute uses bf16 MFMA.
typedef __attribute__((ext_vector_type(8))) short short8;   // 8 bf16 = 4 VGPRs (MFMA A/B frag)
typedef __attribute__((ext_vector_type(4))) float floatx4;  // MFMA C/D frag

#define TBH ((size_t)16777216)  // 32768*512 per-gate G stride (elements)

__device__ __forceinline__ float bfbits2f(unsigned short b) {
  return __uint_as_float(((unsigned int)b) << 16);
}
__device__ __forceinline__ unsigned short f2bf(float f) {
  unsigned int u = __float_as_uint(f);
  unsigned int r = (u + 0x7fffu + ((u >> 16) & 1u)) >> 16;  // RNE
  return (unsigned short)r;
}

// Relaxed device-scope atomics (bypass non-coherent per-XCD caches). Every
// exchanged word is self-synchronizing: h words = bf16<<16 | 16-bit step tag;
// Pr words = f32 partial with 2-bit step tag in mantissa LSBs (err 2^-21).
__device__ __forceinline__ void dev_store(unsigned int* p, unsigned int v) {
  __hip_atomic_store(p, v, __ATOMIC_RELAXED, __HIP_MEMORY_SCOPE_AGENT);
}
__device__ __forceinline__ unsigned int dev_load(const unsigned int* p) {
  return __hip_atomic_load(p, __ATOMIC_RELAXED, __HIP_MEMORY_SCOPE_AGENT);
}

// LDS barrier WITHOUT vmcnt(0) drain: publish stores stay in flight across
// the barrier. lgkmcnt(0) orders LDS. sched_barrier(0) per guide rule #18.
#define LBAR()                                              \
  do {                                                      \
    asm volatile("s_waitcnt lgkmcnt(0)" ::: "memory");      \
    __builtin_amdgcn_s_barrier();                           \
    __builtin_amdgcn_sched_barrier(0);                      \
  } while (0)

// -------------------------------------------------------------------------
// prep: hpub par0 = bf16(h0)|tag0, par1 = sentinel; PrB zero (tag0);
// Whr/Whi/Whn -> bf16.
// -------------------------------------------------------------------------
__global__ void prep_kernel(const float* __restrict__ h0,
                            unsigned int* __restrict__ hpub,
                            unsigned int* __restrict__ PrB,
                            const float* __restrict__ Whr,
                            const float* __restrict__ Whi,
                            const float* __restrict__ Whn,
                            unsigned short* __restrict__ Whb) {
  int i = blockIdx.x * 256 + threadIdx.x;  // grid 1024*256 = 262144
  if (i < 64 * 512) {
    hpub[i] = ((unsigned int)f2bf(h0[i])) << 16;  // parity 0, tag 0 (= h_0)
    hpub[32768 + i] = 0x8000u;                    // parity 1 sentinel (never a real tag)
  }
  PrB[i] = 0u;  // both parities; tag bits 0 != first expected tags {1,2}
#pragma unroll
  for (int rep = 0; rep < 3; ++rep) {
    int j = i + rep * 262144;
    float v = (j < 262144) ? Whr[j] : ((j < 524288) ? Whi[j - 262144] : Whn[j - 524288]);
    Whb[j] = f2bf(v);
  }
}

// -------------------------------------------------------------------------
// Phase 1: G[gate][t*64+b][n] = x@Wi^T + ctx@Wp^T + (bi+bh+bp)   (bf16 out)
// (unchanged)
// -------------------------------------------------------------------------
struct PreArgs {
  const float* x;
  const float* ctx;
  const float* Wi[3];
  const float* Wp[3];
  const float* bi[3];
  const float* bh[3];
  const float* bp[3];
  unsigned short* G;
};

__global__ __launch_bounds__(256) void gemm_pre(PreArgs args) {
  __shared__ short8 a_sm[512];  // [row(128)][sub(4)] : 128x32 bf16
  __shared__ short8 b_sm[512];
  const int tid = threadIdx.x;
  const int gate = blockIdx.z;
  const int n0 = blockIdx.x * 128;
  const int m0 = blockIdx.y * 128;
  const int wave = tid >> 6, lane = tid & 63;
  const int wm = (wave & 1) * 64, wn = (wave >> 1) * 64;
  const int lm = lane & 15, lq = lane >> 4;
  const float* Wi = args.Wi[gate];
  const float* Wp = args.Wp[gate];

  floatx4 acc[4][4];
#pragma unroll
  for (int i = 0; i < 4; ++i)
#pragma unroll
    for (int j = 0; j < 4; ++j) acc[i][j] = floatx4{0.f, 0.f, 0.f, 0.f};

  for (int kb = 0; kb < 32; ++kb) {
    const float* asrc = (kb < 16) ? args.x : args.ctx;
    const float* bsrc = (kb < 16) ? Wi : Wp;
    const int k0 = (kb & 15) * 32;
    __syncthreads();
#pragma unroll
    for (int c = 0; c < 2; ++c) {
      int s = c * 256 + tid;
      int row = s >> 2, sub = s & 3;
      const float* ap = asrc + (size_t)(m0 + row) * 512 + k0 + sub * 8;
      const float* bp = bsrc + (size_t)(n0 + row) * 512 + k0 + sub * 8;
      float4 a0 = *(const float4*)ap, a1 = *(const float4*)(ap + 4);
      float4 b0 = *(const float4*)bp, b1 = *(const float4*)(bp + 4);
      short8 av, bv;
      av[0] = (short)f2bf(a0.x); av[1] = (short)f2bf(a0.y);
      av[2] = (short)f2bf(a0.z); av[3] = (short)f2bf(a0.w);
      av[4] = (short)f2bf(a1.x); av[5] = (short)f2bf(a1.y);
      av[6] = (short)f2bf(a1.z); av[7] = (short)f2bf(a1.w);
      bv[0] = (short)f2bf(b0.x); bv[1] = (short)f2bf(b0.y);
      bv[2] = (short)f2bf(b0.z); bv[3] = (short)f2bf(b0.w);
      bv[4] = (short)f2bf(b1.x); bv[5] = (short)f2bf(b1.y);
      bv[6] = (short)f2bf(b1.z); bv[7] = (short)f2bf(b1.w);
      a_sm[row * 4 + sub] = av;
      b_sm[row * 4 + sub] = bv;
    }
    __syncthreads();
    short8 af[4], bf[4];
#pragma unroll
    for (int i = 0; i < 4; ++i) af[i] = a_sm[(wm + i * 16 + lm) * 4 + lq];
#pragma unroll
    for (int j = 0; j < 4; ++j) bf[j] = b_sm[(wn + j * 16 + lm) * 4 + lq];
#pragma unroll
    for (int i = 0; i < 4; ++i)
#pragma unroll
      for (int j = 0; j < 4; ++j)
        acc[i][j] = __builtin_amdgcn_mfma_f32_16x16x32_bf16(af[i], bf[j], acc[i][j], 0, 0, 0);
  }

#pragma unroll
  for (int j = 0; j < 4; ++j) {
    int n = n0 + wn + j * 16 + lm;
    float bias = args.bi[gate][n] + args.bh[gate][n] + args.bp[gate][n];
#pragma unroll
    for (int i = 0; i < 4; ++i) {
      int mbase = m0 + wm + i * 16 + lq * 4;
#pragma unroll
      for (int r = 0; r < 4; ++r) {
        int m = mbase + r;
        int t = m & 511, b = m >> 9;
        args.G[(size_t)gate * TBH + (size_t)(t * 64 + b) * 512 + n] = f2bf(acc[i][j][r] + bias);
      }
    }
  }
}

// -------------------------------------------------------------------------
// Recurrence: 16 WGs = 4 chains (16 batches) x 4 col slices (128 cols),
// 512 thr = 8 waves. ONE exchange per step: each WG publishes its h-slice
// (bf16|tag) AND its r-gate partial Pr = h_slice @ WhrT (f32, 2-bit mantissa
// tag) computed from LOCAL data at step start. Consumers gather, form full
// r -> full rh locally -> i and n matmuls fully local. Double-buffered by
// step parity (run-ahead <= 1 step proven by the publish/consume chain).
// Weights: Pr-weights + Whn in VGPRs (128), Whi in LDS (128 KB).
// -------------------------------------------------------------------------
__global__ __launch_bounds__(512, 2) void recur_kernel(
    const unsigned short* __restrict__ G,
    const unsigned short* __restrict__ Whb,   // [3][512][512] bf16
    const float* __restrict__ h0,
    unsigned int* __restrict__ hpub,          // [2][64][512] bf16<<16|tag
    unsigned int* __restrict__ PrB,           // [2][4][4][16][512] f32|2b tag
    float* __restrict__ ys,                   // [64][512][512] f32
    float* __restrict__ hT) {                 // [64][512] f32
  __shared__ short8 fragbuf[1024];  // 16 KB: h_full -> rh_full A-frags
  __shared__ short8 iwsm[8192];     // 128 KB: Whi B-frags [wave][kb][lane]

  const int tid = threadIdx.x;
  const int g = blockIdx.x >> 2;   // chain 0..3
  const int cb = blockIdx.x & 3;   // col slice 0..3
  const int b0 = g * 16;
  const int c0 = cb * 128;
  const int wave = tid >> 6, lane = tid & 63;
  const int lm = lane & 15, lq = lane >> 4;
  const int w64 = wave * 64;
  const int kcol = c0 + wave * 16 + lm;  // own i/n output col
  const int prow = lq * 4;

  // ---- Whi -> LDS B-frags ----
  for (int s = tid; s < 8192; s += 512) {
    int wv = s >> 10, kb = (s >> 6) & 15, l = s & 63;
    iwsm[s] = *(const short8*)(Whb + 262144 +
        (size_t)(c0 + (wv << 4) + (l & 15)) * 512 + kb * 32 + (l >> 4) * 8);
  }
  // ---- WhrT (Pr) + Whn -> regs ----
  short8 wpr[4][4], wnw[16];
#pragma unroll
  for (int n = 0; n < 4; ++n)
#pragma unroll
    for (int q = 0; q < 4; ++q)
      wpr[n][q] = *(const short8*)(Whb +
          (size_t)(w64 + n * 16 + lm) * 512 + (cb * 4 + q) * 32 + lq * 8);
#pragma unroll
  for (int kb = 0; kb < 16; ++kb)
    wnw[kb] = *(const short8*)(Whb + 2 * 262144 +
        (size_t)kcol * 512 + kb * 32 + lq * 8);

  // ---- maps ----
  const int srow = tid >> 5;        // remote-h staging (R2-proven)
  const int skk = (tid * 4) & 127;
  const int sl = srow + 16 * ((skk >> 3) & 3);
  const int su2 = ((skk >> 5) * 64 + sl) * 2 + ((skk >> 2) & 1);
  uint2* f2 = (uint2*)fragbuf;
  unsigned short* fus = (unsigned short*)fragbuf;

  int pub[4], ppos[16], pfix[16];
#pragma unroll
  for (int r = 0; r < 4; ++r) pub[r] = (b0 + prow + r) * 512 + kcol;
#pragma unroll
  for (int n = 0; n < 4; ++n)
#pragma unroll
    for (int r = 0; r < 4; ++r) {
      int col = w64 + n * 16 + lm;
      ppos[n * 4 + r] = (prow + r) * 512 + col;
      pfix[n * 4 + r] = (col >> 5) * 512 + ((col >> 3) & 3) * 128 + (col & 7) + (prow + r) * 8;
    }
  const int ecol = (kcol >> 5) * 512 + ((kcol >> 3) & 3) * 128 + (kcol & 7);
  const int groff = b0 * 512;

  // ---- h0: regs + own-slice frags ----
  float hreg[4];
#pragma unroll
  for (int r = 0; r < 4; ++r) hreg[r] = h0[pub[r]];
#pragma unroll
  for (int r = 0; r < 4; ++r) fus[ecol + (prow + r) * 8] = f2bf(hreg[r]);
  __syncthreads();

  // ---- G prefetch (t=0) ----
  unsigned short grc[16], gic[4], gnc[4];
#pragma unroll
  for (int k = 0; k < 16; ++k) grc[k] = G[(size_t)(groff + ppos[k])];
#pragma unroll
  for (int r = 0; r < 4; ++r) {
    gic[r] = G[TBH + (size_t)pub[r]];
    gnc[r] = G[2 * TBH + (size_t)pub[r]];
  }

  for (int t = 0; t < 512; ++t) {
    const unsigned int htag = (unsigned int)t;
    const unsigned int prtag = (unsigned int)((t + 1) & 3);
    const unsigned int* hsrc = hpub + (t & 1) * 32768;
    unsigned int* prdst = PrB + (size_t)(t & 1) * 131072 + g * 32768 + cb * 8192;
    const unsigned int* prsrc = PrB + (size_t)(t & 1) * 131072 + g * 32768;

    // ---- A: Pr partial MFMA from OWN frags (local data only) ----
    floatx4 pr[4];
#pragma unroll
    for (int n = 0; n < 4; ++n) pr[n] = floatx4{0.f, 0.f, 0.f, 0.f};
    short8 hfq[4];
#pragma unroll
    for (int q = 0; q < 4; ++q) hfq[q] = fragbuf[(cb * 4 + q) * 64 + lane];
#pragma unroll
    for (int n = 0; n < 4; ++n)
#pragma unroll
      for (int q = 0; q < 4; ++q)
        pr[n] = __builtin_amdgcn_mfma_f32_16x16x32_bf16(hfq[q], wpr[n][q], pr[n], 0, 0, 0);
    // publish Pr (f32, mantissa tag)
#pragma unroll
    for (int n = 0; n < 4; ++n)
#pragma unroll
      for (int r = 0; r < 4; ++r)
        dev_store((unsigned int*)prdst + ppos[n * 4 + r],
                  (__float_as_uint(pr[n][r]) & 0xFFFFFFFCu) | prtag);

    // ---- issue poll loads: remote h (12) then remote Pr (48) ----
    unsigned int hv[12];
    const unsigned int* hb = hsrc + (unsigned)(b0 + srow) * 512;
#pragma unroll
    for (int s = 0; s < 3; ++s) {
      const int off = (((cb + 1 + s) & 3) << 7) + skk;
#pragma unroll
      for (int j = 0; j < 4; ++j) hv[s * 4 + j] = dev_load(hb + off + j);
    }
    unsigned int pv[48];
#pragma unroll
    for (int s = 0; s < 3; ++s) {
      const int sb = ((cb + 1 + s) & 3) * 8192;
#pragma unroll
      for (int k = 0; k < 16; ++k) pv[s * 16 + k] = dev_load(prsrc + sb + ppos[k]);
    }

    // ---- poll h (per-slice retry), stage remote h frags ----
    for (;;) {
      bool ok = true;
#pragma unroll
      for (int i = 0; i < 12; ++i) ok &= ((hv[i] & 0xffffu) == htag);
      if (ok) break;
#pragma unroll
      for (int s = 0; s < 3; ++s) {
        bool st = false;
#pragma unroll
        for (int j = 0; j < 4; ++j) st |= ((hv[s * 4 + j] & 0xffffu) != htag);
        if (st) {
          const int off = (((cb + 1 + s) & 3) << 7) + skk;
#pragma unroll
          for (int j = 0; j < 4; ++j) hv[s * 4 + j] = dev_load(hb + off + j);
        }
      }
    }
#pragma unroll
    for (int s = 0; s < 3; ++s) {
      const int rcb = (cb + 1 + s) & 3;
      uint2 p;
      p.x = (hv[s * 4 + 0] >> 16) | (hv[s * 4 + 1] & 0xffff0000u);
      p.y = (hv[s * 4 + 2] >> 16) | (hv[s * 4 + 3] & 0xffff0000u);
      f2[su2 + rcb * 512] = p;
    }
    LBAR();  // (1) h_full staged

    // ---- i-gate MFMA (LDS weights) while Pr loads fly ----
    floatx4 ia = {0.f, 0.f, 0.f, 0.f};
#pragma unroll
    for (int kb = 0; kb < 16; ++kb)
      ia = __builtin_amdgcn_mfma_f32_16x16x32_bf16(
          fragbuf[kb * 64 + lane], iwsm[(wave * 16 + kb) * 64 + lane], ia, 0, 0, 0);

    // ---- poll Pr (per-sibling retry) ----
    for (;;) {
      bool ok = true;
#pragma unroll
      for (int i = 0; i < 48; ++i) ok &= ((pv[i] & 3u) == prtag);
      if (ok) break;
#pragma unroll
      for (int s = 0; s < 3; ++s) {
        bool st = false;
#pragma unroll
        for (int k = 0; k < 16; ++k) st |= ((pv[s * 16 + k] & 3u) != prtag);
        if (st) {
          const int sb = ((cb + 1 + s) & 3) * 8192;
#pragma unroll
          for (int k = 0; k < 16; ++k) pv[s * 16 + k] = dev_load(prsrc + sb + ppos[k]);
        }
      }
    }

    // ---- r = sigmoid(G_r + 4 partials); rh = r*h (h from LDS) ----
    unsigned short rhb[16];
#pragma unroll
    for (int k = 0; k < 16; ++k) {
      int n = k >> 2, r = k & 3;
      float rsum = pr[n][r] + bfbits2f(grc[k]) +
                   __uint_as_float(pv[k] & 0xFFFFFFFCu) +
                   __uint_as_float(pv[16 + k] & 0xFFFFFFFCu) +
                   __uint_as_float(pv[32 + k] & 0xFFFFFFFCu);
      float rv = 1.f / (1.f + __expf(-rsum));
      rhb[k] = f2bf(rv * bfbits2f(fus[pfix[k]]));
    }
    float ireg[4];
#pragma unroll
    for (int r = 0; r < 4; ++r) ireg[r] = 1.f / (1.f + __expf(-(ia[r] + bfbits2f(gic[r]))));
    LBAR();  // (2) all h reads (i-MFMA + rh) done

    // ---- scatter rh over fragbuf (full rewrite, all cols) ----
#pragma unroll
    for (int k = 0; k < 16; ++k) fus[pfix[k]] = rhb[k];
    LBAR();  // (3) rh_full staged

    // ---- n-gate MFMA (reg weights) ----
    floatx4 na = {0.f, 0.f, 0.f, 0.f};
#pragma unroll
    for (int kb = 0; kb < 16; ++kb)
      na = __builtin_amdgcn_mfma_f32_16x16x32_bf16(
          fragbuf[kb * 64 + lane], wnw[kb], na, 0, 0, 0);

    // ---- G prefetch for t+1 (issued early: never gates next poll) ----
    const int tp = (t + 1 < 512) ? t + 1 : 511;
    unsigned short grn[16], gin[4], gnn[4];
#pragma unroll
    for (int k = 0; k < 16; ++k) grn[k] = G[(size_t)tp * 32768 + groff + ppos[k]];
#pragma unroll
    for (int r = 0; r < 4; ++r) {
      gin[r] = G[TBH + (size_t)tp * 32768 + pub[r]];
      gnn[r] = G[2 * TBH + (size_t)tp * 32768 + pub[r]];
    }
    LBAR();  // (4) all n-MFMA reads done before own-h scatter

    // ---- epilogue: tanh, blend, publish h(t+1), ys, own-h frags ----
    unsigned int* hdst = hpub + ((t + 1) & 1) * 32768;
#pragma unroll
    for (int r = 0; r < 4; ++r) {
      float pre = na[r] + bfbits2f(gnc[r]);
      float e = __expf(2.f * pre);
      float nv = 1.f - 2.f / (e + 1.f);  // tanh
      float hy = (1.f - ireg[r]) * hreg[r] + ireg[r] * nv;
      hreg[r] = hy;
      unsigned short hbits = f2bf(hy);
      dev_store(hdst + pub[r], (((unsigned int)hbits) << 16) | (unsigned int)(t + 1));
      fus[ecol + (prow + r) * 8] = hbits;
      ys[(size_t)(b0 + prow + r) * 262144 + (size_t)t * 512 + kcol] = hy;
    }
    if (t == 511) {
#pragma unroll
      for (int r = 0; r < 4; ++r) hT[pub[r]] = hreg[r];
    }
#pragma unroll
    for (int k = 0; k < 16; ++k) grc[k] = grn[k];
#pragma unroll
    for (int r = 0; r < 4; ++r) { gic[r] = gin[r]; gnc[r] = gnn[r]; }
    LBAR();  // (5) own-h frags visible for next step's Pr-MFMA
  }
}

// -------------------------------------------------------------------------
extern "C" void kernel_launch(void* const* d_in, const int* in_sizes, int n_in,
                              void* d_out, int out_size, void* d_ws, size_t ws_size,
                              hipStream_t stream) {
  typedef const float* cfp;
  cfp x = (cfp)d_in[0];
  cfp h0 = (cfp)d_in[1];
  cfp ctx = (cfp)d_in[2];

  PreArgs pa;
  pa.x = x;
  pa.ctx = ctx;
  for (int gi = 0; gi < 3; ++gi) {
    pa.Wi[gi] = (cfp)d_in[3 + 6 * gi];
    pa.bi[gi] = (cfp)d_in[4 + 6 * gi];
    pa.bh[gi] = (cfp)d_in[6 + 6 * gi];
    pa.Wp[gi] = (cfp)d_in[7 + 6 * gi];
    pa.bp[gi] = (cfp)d_in[8 + 6 * gi];
  }
  cfp Whr = (cfp)d_in[5], Whi = (cfp)d_in[11], Whn = (cfp)d_in[17];

  char* ws = (char*)d_ws;
  unsigned short* G = (unsigned short*)ws;          // 3 gates x 32 MB bf16
  size_t off = (size_t)3 * TBH * 2;                 // 100,663,296 B
  unsigned short* Whb = (unsigned short*)(ws + off);
  off += (size_t)3 * 262144 * 2;                    // 1,572,864 B
  unsigned int* hpub = (unsigned int*)(ws + off);
  off += (size_t)2 * 64 * 512 * 4;                  // 262,144 B
  unsigned int* PrB = (unsigned int*)(ws + off);
  off += (size_t)2 * 4 * 4 * 16 * 512 * 4;          // 1,048,576 B
  pa.G = G;

  float* out = (float*)d_out;
  float* ys = out;
  float* hT = out + (size_t)64 * 512 * 512;

  prep_kernel<<<1024, 256, 0, stream>>>(h0, hpub, PrB, Whr, Whi, Whn, Whb);
  dim3 gp(4, 256, 3);
  gemm_pre<<<gp, 256, 0, stream>>>(pa);
  recur_kernel<<<16, 512, 0, stream>>>(G, Whb, h0, hpub, PrB, ys, hT);
}

// Round 4
// 10232.627 us; speedup vs baseline: 1.0514x; 1.0514x over previous
//
#include <hip/hip_runtime.h>
#include <hip/hip_bf16.h>

// Inputs/outputs are FLOAT32 (per reference). Compute uses bf16 MFMA.
typedef __attribute__((ext_vector_type(8))) short short8;   // 8 bf16 = 4 VGPRs (MFMA A/B frag)
typedef __attribute__((ext_vector_type(4))) float floatx4;  // MFMA C/D frag
typedef __attribute__((ext_vector_type(4))) unsigned int uintx4;

#define TBH ((size_t)16777216)  // 32768*512 per-gate G stride (elements)

__device__ __forceinline__ float bfbits2f(unsigned short b) {
  return __uint_as_float(((unsigned int)b) << 16);
}
__device__ __forceinline__ unsigned short f2bf(float f) {
  unsigned int u = __float_as_uint(f);
  unsigned int r = (u + 0x7fffu + ((u >> 16) & 1u)) >> 16;  // RNE
  return (unsigned short)r;
}

// SLOW path: relaxed agent-scope atomics (coherence point = Infinity Cache;
// works across XCDs). FAST path (same-XCD proven at runtime): plain stores
// (write-through to the shared per-XCD L2) + sc0 loads (bypass L1, read L2).
__device__ __forceinline__ void dev_store(unsigned int* p, unsigned int v) {
  __hip_atomic_store(p, v, __ATOMIC_RELAXED, __HIP_MEMORY_SCOPE_AGENT);
}
__device__ __forceinline__ unsigned int dev_load(const unsigned int* p) {
  return __hip_atomic_load(p, __ATOMIC_RELAXED, __HIP_MEMORY_SCOPE_AGENT);
}

template <bool FAST>
__device__ __forceinline__ void exst(unsigned int* p, unsigned int v) {
  if constexpr (FAST) {
    *(volatile unsigned int*)p = v;  // global_store_dword -> local L2
  } else {
    dev_store(p, v);
  }
}

template <bool FAST>
__device__ __forceinline__ uintx4 exld4(const unsigned int* p) {
  uintx4 r;
  if constexpr (FAST) {
    asm volatile("global_load_dwordx4 %0, %1, off sc0\n\ts_waitcnt vmcnt(0)"
                 : "=&v"(r) : "v"(p) : "memory");
  } else {
    r[0] = dev_load(p); r[1] = dev_load(p + 1);
    r[2] = dev_load(p + 2); r[3] = dev_load(p + 3);
  }
  return r;
}

template <bool FAST>
__device__ __forceinline__ void exld4x3(const unsigned int* p0, const unsigned int* p1,
                                        const unsigned int* p2,
                                        uintx4& a, uintx4& b, uintx4& c) {
  if constexpr (FAST) {
    asm volatile(
        "global_load_dwordx4 %0, %3, off sc0\n\t"
        "global_load_dwordx4 %1, %4, off sc0\n\t"
        "global_load_dwordx4 %2, %5, off sc0\n\t"
        "s_waitcnt vmcnt(0)"
        : "=&v"(a), "=&v"(b), "=&v"(c)
        : "v"(p0), "v"(p1), "v"(p2) : "memory");
  } else {
    a = exld4<false>(p0); b = exld4<false>(p1); c = exld4<false>(p2);
  }
}

__device__ __forceinline__ bool tagok(uintx4 v, unsigned int tag) {
  return ((v[0] & 0xffffu) == tag) & ((v[1] & 0xffffu) == tag) &
         ((v[2] & 0xffffu) == tag) & ((v[3] & 0xffffu) == tag);
}

// LDS barrier WITHOUT vmcnt(0) drain: publish stores stay in flight across
// the barrier. lgkmcnt(0) orders LDS. sched_barrier(0) per guide rule #18.
#define LBAR()                                              \
  do {                                                      \
    asm volatile("s_waitcnt lgkmcnt(0)" ::: "memory");      \
    __builtin_amdgcn_s_barrier();                           \
    __builtin_amdgcn_sched_barrier(0);                      \
  } while (0)

// -------------------------------------------------------------------------
// prep: hpub = bf16(h0)|tag0 ; rhpub = 0 ; aux (xcd/ping/verdict) = 0;
// Whr/Whi/Whn -> bf16.
// -------------------------------------------------------------------------
__global__ void prep_kernel(const float* __restrict__ h0,
                            unsigned int* __restrict__ hpub,
                            unsigned int* __restrict__ rhpub,
                            unsigned int* __restrict__ aux,
                            const float* __restrict__ Whr,
                            const float* __restrict__ Whi,
                            const float* __restrict__ Whn,
                            unsigned short* __restrict__ Whb) {
  int i = blockIdx.x * 256 + threadIdx.x;  // grid 1024*256 = 262144
  if (i < 64 * 512) {
    hpub[i] = ((unsigned int)f2bf(h0[i])) << 16;  // tag 0 == h_0
    rhpub[i] = 0u;                                // != first rh tag (1)
  }
  if (i < 576) aux[i] = 0u;
#pragma unroll
  for (int rep = 0; rep < 3; ++rep) {
    int j = i + rep * 262144;
    float v = (j < 262144) ? Whr[j] : ((j < 524288) ? Whi[j - 262144] : Whn[j - 524288]);
    Whb[j] = f2bf(v);
  }
}

// -------------------------------------------------------------------------
// Phase 1: G[gate][t*64+b][n] = x@Wi^T + ctx@Wp^T + (bi+bh+bp)   (bf16 out)
// (unchanged)
// -------------------------------------------------------------------------
struct PreArgs {
  const float* x;
  const float* ctx;
  const float* Wi[3];
  const float* Wp[3];
  const float* bi[3];
  const float* bh[3];
  const float* bp[3];
  unsigned short* G;
};

__global__ __launch_bounds__(256) void gemm_pre(PreArgs args) {
  __shared__ short8 a_sm[512];  // [row(128)][sub(4)] : 128x32 bf16
  __shared__ short8 b_sm[512];
  const int tid = threadIdx.x;
  const int gate = blockIdx.z;
  const int n0 = blockIdx.x * 128;
  const int m0 = blockIdx.y * 128;
  const int wave = tid >> 6, lane = tid & 63;
  const int wm = (wave & 1) * 64, wn = (wave >> 1) * 64;
  const int lm = lane & 15, lq = lane >> 4;
  const float* Wi = args.Wi[gate];
  const float* Wp = args.Wp[gate];

  floatx4 acc[4][4];
#pragma unroll
  for (int i = 0; i < 4; ++i)
#pragma unroll
    for (int j = 0; j < 4; ++j) acc[i][j] = floatx4{0.f, 0.f, 0.f, 0.f};

  for (int kb = 0; kb < 32; ++kb) {
    const float* asrc = (kb < 16) ? args.x : args.ctx;
    const float* bsrc = (kb < 16) ? Wi : Wp;
    const int k0 = (kb & 15) * 32;
    __syncthreads();
#pragma unroll
    for (int c = 0; c < 2; ++c) {
      int s = c * 256 + tid;
      int row = s >> 2, sub = s & 3;
      const float* ap = asrc + (size_t)(m0 + row) * 512 + k0 + sub * 8;
      const float* bp = bsrc + (size_t)(n0 + row) * 512 + k0 + sub * 8;
      float4 a0 = *(const float4*)ap, a1 = *(const float4*)(ap + 4);
      float4 b0 = *(const float4*)bp, b1 = *(const float4*)(bp + 4);
      short8 av, bv;
      av[0] = (short)f2bf(a0.x); av[1] = (short)f2bf(a0.y);
      av[2] = (short)f2bf(a0.z); av[3] = (short)f2bf(a0.w);
      av[4] = (short)f2bf(a1.x); av[5] = (short)f2bf(a1.y);
      av[6] = (short)f2bf(a1.z); av[7] = (short)f2bf(a1.w);
      bv[0] = (short)f2bf(b0.x); bv[1] = (short)f2bf(b0.y);
      bv[2] = (short)f2bf(b0.z); bv[3] = (short)f2bf(b0.w);
      bv[4] = (short)f2bf(b1.x); bv[5] = (short)f2bf(b1.y);
      bv[6] = (short)f2bf(b1.z); bv[7] = (short)f2bf(b1.w);
      a_sm[row * 4 + sub] = av;
      b_sm[row * 4 + sub] = bv;
    }
    __syncthreads();
    short8 af[4], bf[4];
#pragma unroll
    for (int i = 0; i < 4; ++i) af[i] = a_sm[(wm + i * 16 + lm) * 4 + lq];
#pragma unroll
    for (int j = 0; j < 4; ++j) bf[j] = b_sm[(wn + j * 16 + lm) * 4 + lq];
#pragma unroll
    for (int i = 0; i < 4; ++i)
#pragma unroll
      for (int j = 0; j < 4; ++j)
        acc[i][j] = __builtin_amdgcn_mfma_f32_16x16x32_bf16(af[i], bf[j], acc[i][j], 0, 0, 0);
  }

#pragma unroll
  for (int j = 0; j < 4; ++j) {
    int n = n0 + wn + j * 16 + lm;
    float bias = args.bi[gate][n] + args.bh[gate][n] + args.bp[gate][n];
#pragma unroll
    for (int i = 0; i < 4; ++i) {
      int mbase = m0 + wm + i * 16 + lq * 4;
#pragma unroll
      for (int r = 0; r < 4; ++r) {
        int m = mbase + r;
        int t = m & 511, b = m >> 9;
        args.G[(size_t)gate * TBH + (size_t)(t * 64 + b) * 512 + n] = f2bf(acc[i][j][r] + bias);
      }
    }
  }
}

// -------------------------------------------------------------------------
// Recurrence body: 32 WGs = 8 chains (8 batches) x 4 col slices (128 cols),
// 512 thr = 8 waves. Siblings of a chain at bid == chain (mod 8) -> same XCD
// under round-robin dispatch; FAST exchanges via local L2 (plain store /
// sc0 load), SLOW via agent scope. Two tagged handoffs per step (h, r*h).
// fragbuf rows 8..15 permanently zero (8-batch chains, 16-row MFMA tiles).
// -------------------------------------------------------------------------
template <bool FAST>
__device__ __forceinline__ void recur_body(
    const unsigned short* __restrict__ G,
    const unsigned short* __restrict__ Whb,
    const float* __restrict__ h0,
    unsigned int* __restrict__ hpub,
    unsigned int* __restrict__ rhpub,
    float* __restrict__ ys,
    float* __restrict__ hT,
    short8* fragbuf) {
  const int tid = threadIdx.x;
  const int bid = blockIdx.x;
  const int c = bid & 7;       // chain
  const int cb = bid >> 3;     // col slice 0..3
  const int b0 = c * 8;
  const int c0 = cb * 128;
  const int wave = tid >> 6, lane = tid & 63;
  const int lm = lane & 15, lq = lane >> 4;
  const int kcol = c0 + wave * 16 + lm;
  const int prow = lq * 4;
  const bool pv = (lq < 2);  // rows 0..7 valid

  // ---- weights (R2 layout): per-wave 16 cols, all 3 gates ----
  const unsigned short* Wb = Whb + (size_t)kcol * 512 + lq * 8;
  short8 wrl[4], wil[4], wnl[4], wrr[12], wir[12], wnr[12];
#pragma unroll
  for (int q = 0; q < 4; ++q) {
    const int kb = cb * 4 + q;
    wrl[q] = *(const short8*)(Wb + 0 * 262144 + kb * 32);
    wil[q] = *(const short8*)(Wb + 1 * 262144 + kb * 32);
    wnl[q] = *(const short8*)(Wb + 2 * 262144 + kb * 32);
  }
#pragma unroll
  for (int j = 0; j < 12; ++j) {
    const int kb = (((cb + 1 + (j >> 2)) & 3) << 2) + (j & 3);
    wrr[j] = *(const short8*)(Wb + 0 * 262144 + kb * 32);
    wir[j] = *(const short8*)(Wb + 1 * 262144 + kb * 32);
    wnr[j] = *(const short8*)(Wb + 2 * 262144 + kb * 32);
  }

  // ---- staging map (tid<256 => waves 0..3, wave-uniform) ----
  const int srow = tid >> 5;        // 0..7 (valid only tid<256)
  const int skk = (tid * 4) & 127;
  const int sl = srow + 16 * ((skk >> 3) & 3);
  const int su2 = ((skk >> 5) * 64 + sl) * 2 + ((skk >> 2) & 1);
  const int rcb0 = (cb + 1) & 3, rcb1 = (cb + 2) & 3, rcb2 = (cb + 3) & 3;
  const int roff0 = (b0 + srow) * 512 + rcb0 * 128 + skk;
  const int roff1 = (b0 + srow) * 512 + rcb1 * 128 + skk;
  const int roff2 = (b0 + srow) * 512 + rcb2 * 128 + skk;
  uint2* f2 = (uint2*)fragbuf;
  unsigned short* fus = (unsigned short*)fragbuf;
  const int ecol = (kcol >> 5) * 512 + ((kcol >> 3) & 3) * 128 + (kcol & 7);

  int pub[4];
#pragma unroll
  for (int r = 0; r < 4; ++r) pub[r] = (b0 + prow + r) * 512 + kcol;

  // ---- zero fragbuf (rows 8..15 stay zero forever) ----
#pragma unroll
  for (int k = 0; k < 4; ++k) f2[tid + 512 * k] = uint2{0u, 0u};
  __syncthreads();

  // ---- h0 into regs + own-slice frags; G(t=0) prefetch ----
  float hreg[4] = {0.f, 0.f, 0.f, 0.f}, ireg[4];
  unsigned short grc[4], gic[4], gnc[4];
  if (pv) {
#pragma unroll
    for (int r = 0; r < 4; ++r) {
      hreg[r] = h0[pub[r]];
      fus[ecol + (prow + r) * 8] = f2bf(hreg[r]);
    }
    const unsigned short* Gt = G + (size_t)(b0 + prow) * 512 + kcol;
#pragma unroll
    for (int r = 0; r < 4; ++r) {
      grc[r] = Gt[r * 512];
      gic[r] = Gt[TBH + r * 512];
      gnc[r] = Gt[2 * TBH + r * 512];
    }
  }
  __syncthreads();

  for (int t = 0; t < 512; ++t) {
    const unsigned int htag = (unsigned int)t;
    const unsigned int rtag = (unsigned int)(t + 1);

    // ======== phase A ========
    uintx4 hv0, hv1, hv2;
    if (tid < 256) exld4x3<FAST>(hpub + roff0, hpub + roff1, hpub + roff2, hv0, hv1, hv2);
    // local r,i MFMAs while loads fly
    floatx4 ar = {0.f, 0.f, 0.f, 0.f}, ai = {0.f, 0.f, 0.f, 0.f};
    short8 hfq[4];
#pragma unroll
    for (int q = 0; q < 4; ++q) hfq[q] = fragbuf[(cb * 4 + q) * 64 + lane];
#pragma unroll
    for (int q = 0; q < 4; ++q) {
      ar = __builtin_amdgcn_mfma_f32_16x16x32_bf16(hfq[q], wrl[q], ar, 0, 0, 0);
      ai = __builtin_amdgcn_mfma_f32_16x16x32_bf16(hfq[q], wil[q], ai, 0, 0, 0);
    }
    if (tid < 256) {
      for (;;) {
        bool o0 = tagok(hv0, htag), o1 = tagok(hv1, htag), o2 = tagok(hv2, htag);
        if (o0 & o1 & o2) break;
        if (!o0) hv0 = exld4<FAST>(hpub + roff0);
        if (!o1) hv1 = exld4<FAST>(hpub + roff1);
        if (!o2) hv2 = exld4<FAST>(hpub + roff2);
      }
      uint2 p;
      p.x = (hv0[0] >> 16) | (hv0[1] & 0xffff0000u);
      p.y = (hv0[2] >> 16) | (hv0[3] & 0xffff0000u);
      f2[su2 + rcb0 * 512] = p;
      p.x = (hv1[0] >> 16) | (hv1[1] & 0xffff0000u);
      p.y = (hv1[2] >> 16) | (hv1[3] & 0xffff0000u);
      f2[su2 + rcb1 * 512] = p;
      p.x = (hv2[0] >> 16) | (hv2[1] & 0xffff0000u);
      p.y = (hv2[2] >> 16) | (hv2[3] & 0xffff0000u);
      f2[su2 + rcb2 * 512] = p;
    }
    // G(t+1) prefetch issued here: a full phase-B of compute before any
    // poll's vmcnt(0) can drain it.
    const int tp = (t + 1 < 512) ? t + 1 : 511;
    unsigned short grn[4], gin[4], gnn[4];
    if (pv) {
      const unsigned short* Gt1 = G + (size_t)(tp * 64 + b0 + prow) * 512 + kcol;
#pragma unroll
      for (int r = 0; r < 4; ++r) {
        grn[r] = Gt1[r * 512];
        gin[r] = Gt1[TBH + r * 512];
        gnn[r] = Gt1[2 * TBH + r * 512];
      }
    }
    LBAR();  // (1) full h staged

    // remote r,i MFMAs
#pragma unroll
    for (int j = 0; j < 12; ++j) {
      const int kb = (((cb + 1 + (j >> 2)) & 3) << 2) + (j & 3);
      short8 hf = fragbuf[kb * 64 + lane];
      ar = __builtin_amdgcn_mfma_f32_16x16x32_bf16(hf, wrr[j], ar, 0, 0, 0);
      ai = __builtin_amdgcn_mfma_f32_16x16x32_bf16(hf, wir[j], ai, 0, 0, 0);
    }
    // epilogue A: sigmoid; publish rh; keep i in regs
    unsigned short rhb[4];
    if (pv) {
#pragma unroll
      for (int r = 0; r < 4; ++r) {
        float sv = 1.f / (1.f + __expf(-(ar[r] + bfbits2f(grc[r]))));
        ireg[r] = 1.f / (1.f + __expf(-(ai[r] + bfbits2f(gic[r]))));
        rhb[r] = f2bf(sv * hreg[r]);
        exst<FAST>(rhpub + pub[r], (((unsigned int)rhb[r]) << 16) | rtag);
      }
    }
    LBAR();  // (2) all h-frag reads done
    if (pv) {
#pragma unroll
      for (int r = 0; r < 4; ++r) fus[ecol + (prow + r) * 8] = rhb[r];
    }
    LBAR();  // (3) own rh staged

    // ======== phase B ========
    uintx4 rv0, rv1, rv2;
    if (tid < 256) exld4x3<FAST>(rhpub + roff0, rhpub + roff1, rhpub + roff2, rv0, rv1, rv2);
    floatx4 an = {0.f, 0.f, 0.f, 0.f};
#pragma unroll
    for (int q = 0; q < 4; ++q)
      an = __builtin_amdgcn_mfma_f32_16x16x32_bf16(
          fragbuf[(cb * 4 + q) * 64 + lane], wnl[q], an, 0, 0, 0);
    if (tid < 256) {
      for (;;) {
        bool o0 = tagok(rv0, rtag), o1 = tagok(rv1, rtag), o2 = tagok(rv2, rtag);
        if (o0 & o1 & o2) break;
        if (!o0) rv0 = exld4<FAST>(rhpub + roff0);
        if (!o1) rv1 = exld4<FAST>(rhpub + roff1);
        if (!o2) rv2 = exld4<FAST>(rhpub + roff2);
      }
      uint2 p;
      p.x = (rv0[0] >> 16) | (rv0[1] & 0xffff0000u);
      p.y = (rv0[2] >> 16) | (rv0[3] & 0xffff0000u);
      f2[su2 + rcb0 * 512] = p;
      p.x = (rv1[0] >> 16) | (rv1[1] & 0xffff0000u);
      p.y = (rv1[2] >> 16) | (rv1[3] & 0xffff0000u);
      f2[su2 + rcb1 * 512] = p;
      p.x = (rv2[0] >> 16) | (rv2[1] & 0xffff0000u);
      p.y = (rv2[2] >> 16) | (rv2[3] & 0xffff0000u);
      f2[su2 + rcb2 * 512] = p;
    }
    LBAR();  // (4) full rh staged

#pragma unroll
    for (int j = 0; j < 12; ++j) {
      const int kb = (((cb + 1 + (j >> 2)) & 3) << 2) + (j & 3);
      an = __builtin_amdgcn_mfma_f32_16x16x32_bf16(
          fragbuf[kb * 64 + lane], wnr[j], an, 0, 0, 0);
    }
    LBAR();  // (5) all rh-frag reads done before own-h scatter

    // epilogue B: tanh, blend, publish h(t+1), ys, own-h frags
    if (pv) {
#pragma unroll
      for (int r = 0; r < 4; ++r) {
        float pre = an[r] + bfbits2f(gnc[r]);
        float e = __expf(2.f * pre);
        float nv = 1.f - 2.f / (e + 1.f);  // tanh
        float hy = (1.f - ireg[r]) * hreg[r] + ireg[r] * nv;
        hreg[r] = hy;
        unsigned short hb = f2bf(hy);
        exst<FAST>(hpub + pub[r], (((unsigned int)hb) << 16) | rtag);
        fus[ecol + (prow + r) * 8] = hb;
        ys[(size_t)(b0 + prow + r) * 262144 + (size_t)t * 512 + kcol] = hy;
      }
      if (t == 511) {
#pragma unroll
        for (int r = 0; r < 4; ++r) hT[pub[r]] = hreg[r];
      }
#pragma unroll
      for (int r = 0; r < 4; ++r) { grc[r] = grn[r]; gic[r] = gin[r]; gnc[r] = gnn[r]; }
    }
    LBAR();  // (6) own h(t+1) frags visible for next step's local MFMAs
  }
}

__global__ __launch_bounds__(512, 2) void recur_kernel(
    const unsigned short* __restrict__ G,
    const unsigned short* __restrict__ Whb,
    const float* __restrict__ h0,
    unsigned int* __restrict__ hpub,
    unsigned int* __restrict__ rhpub,
    unsigned int* __restrict__ aux,   // [0..31] xcd, [32..543] ping, [544..575] verdict
    float* __restrict__ ys,
    float* __restrict__ hT) {
  __shared__ short8 fragbuf[1024];  // 16 KB
  __shared__ int fastsh;
  const int bid = blockIdx.x;

  // ---- chain-uniform fast/slow agreement ----
  if (threadIdx.x == 0) {
    unsigned int* xcdb = aux;
    unsigned int* pingb = aux + 32;
    unsigned int* verd = aux + 544;
    unsigned int myx;
    asm volatile("s_getreg_b32 %0, hwreg(HW_REG_XCC_ID)" : "=s"(myx));
    dev_store(&xcdb[bid], (myx & 0xffu) | 0x100u);
    unsigned int xs[4];
    for (int s = 0; s < 4; ++s) {
      unsigned int q;
      do { q = dev_load(&xcdb[(bid & 7) + (s << 3)]); } while (q < 0x100u);
      xs[s] = q;
    }
    unsigned int okv = (xs[0] == xs[1]) & (xs[1] == xs[2]) & (xs[2] == xs[3]);
    if (okv) {
      int budget = 40000;
      for (int round = 1; round <= 8 && okv; ++round) {
        *(volatile unsigned int*)&pingb[bid * 16] = (unsigned int)round;
        for (int s = 0; s < 4 && okv; ++s) {
          const unsigned int* pp = &pingb[((bid & 7) + (s << 3)) * 16];
          unsigned int q;
          for (;;) {
            asm volatile("global_load_dword %0, %1, off sc0\n\ts_waitcnt vmcnt(0)"
                         : "=&v"(q) : "v"(pp) : "memory");
            if (q >= (unsigned int)round) break;
            if (--budget <= 0) { okv = 0u; break; }
          }
        }
      }
    }
    dev_store(&verd[bid], okv | 0x100u);
    unsigned int allok = 1u;
    for (int s = 0; s < 4; ++s) {
      unsigned int q;
      do { q = dev_load(&verd[(bid & 7) + (s << 3)]); } while (q < 0x100u);
      allok &= (q & 1u);
    }
    fastsh = (int)allok;
  }
  __syncthreads();

  if (fastsh)
    recur_body<true>(G, Whb, h0, hpub, rhpub, ys, hT, fragbuf);
  else
    recur_body<false>(G, Whb, h0, hpub, rhpub, ys, hT, fragbuf);
}

// -------------------------------------------------------------------------
extern "C" void kernel_launch(void* const* d_in, const int* in_sizes, int n_in,
                              void* d_out, int out_size, void* d_ws, size_t ws_size,
                              hipStream_t stream) {
  typedef const float* cfp;
  cfp x = (cfp)d_in[0];
  cfp h0 = (cfp)d_in[1];
  cfp ctx = (cfp)d_in[2];

  PreArgs pa;
  pa.x = x;
  pa.ctx = ctx;
  for (int gi = 0; gi < 3; ++gi) {
    pa.Wi[gi] = (cfp)d_in[3 + 6 * gi];
    pa.bi[gi] = (cfp)d_in[4 + 6 * gi];
    pa.bh[gi] = (cfp)d_in[6 + 6 * gi];
    pa.Wp[gi] = (cfp)d_in[7 + 6 * gi];
    pa.bp[gi] = (cfp)d_in[8 + 6 * gi];
  }
  cfp Whr = (cfp)d_in[5], Whi = (cfp)d_in[11], Whn = (cfp)d_in[17];

  char* ws = (char*)d_ws;
  unsigned short* G = (unsigned short*)ws;          // 3 gates x 32 MB bf16
  size_t off = (size_t)3 * TBH * 2;                 // 100,663,296 B
  unsigned short* Whb = (unsigned short*)(ws + off);
  off += (size_t)3 * 262144 * 2;                    // 1,572,864 B
  unsigned int* hpub = (unsigned int*)(ws + off);
  off += (size_t)64 * 512 * 4;
  unsigned int* rhpub = (unsigned int*)(ws + off);
  off += (size_t)64 * 512 * 4;
  unsigned int* aux = (unsigned int*)(ws + off);
  off += (size_t)576 * 4;
  pa.G = G;

  float* out = (float*)d_out;
  float* ys = out;
  float* hT = out + (size_t)64 * 512 * 512;

  prep_kernel<<<1024, 256, 0, stream>>>(h0, hpub, rhpub, aux, Whr, Whi, Whn, Whb);
  dim3 gp(4, 256, 3);
  gemm_pre<<<gp, 256, 0, stream>>>(pa);
  recur_kernel<<<32, 512, 0, stream>>>(G, Whb, h0, hpub, rhpub, aux, ys, hT);
}